// Round 13
// baseline (330.085 us; speedup 1.0000x reference)
//
#include <hip/hip_runtime.h>

#define DEVI __device__ __forceinline__

typedef __attribute__((ext_vector_type(8))) short short8;
typedef __attribute__((ext_vector_type(4))) float f32x4;
typedef unsigned short u16;
typedef __attribute__((ext_vector_type(4))) u16 us4;
typedef __attribute__((ext_vector_type(8))) u16 us8;

#define MFMA16(a, b, c) __builtin_amdgcn_mfma_f32_16x16x32_f16(a, b, c, 0, 0, 0)

DEVI u16 hbits(float x) {
    union { _Float16 h; u16 u; } cv;
    cv.h = (_Float16)x;
    return cv.u;
}
DEVI float h2f(u16 u) {
    union { u16 u; _Float16 h; } cv;
    cv.u = u;
    return (float)cv.h;
}

DEVI void gload16(const void* g, void* l) {
    __builtin_amdgcn_global_load_lds(
        (const __attribute__((address_space(1))) unsigned int*)g,
        (__attribute__((address_space(3))) unsigned int*)l, 16, 0, 0);
}

// ---- layouts ----
// Attention fp16 block (64-wide): [128 r][64 k] u16[8192]: idx = (r*64+k) ^ ((r&7)<<3)
// GEMM fp16 block (BK=32): [128 r][32 k] u16[4096] (8 KB):
//   granule g = k>>3 (16B); idx = r*32 + ((g ^ ((r>>1)&3))<<3) + (k&7)
//   -> ds_read_b128 of 16 rows spans all 8 bank-quads (2-way max, free).
// P tiles 64x64 (4096 u16): idx = (r*64+c) ^ ((r&7)<<3).

// All fp32->fp16 conversions into BK=32 GEMM-blocked buffers.
__global__ __launch_bounds__(256) void cvtall(
    const float* __restrict__ hs, const float* __restrict__ Wq, const float* __restrict__ Wk,
    const float* __restrict__ Wv, const float* __restrict__ Wo,
    u16* __restrict__ hs_c, u16* __restrict__ Wqkv_c, u16* __restrict__ Wo_c)
{
    const long t = (long)blockIdx.x * 256 + threadIdx.x;
    const int row = (int)(t >> 8), kg = (int)(t & 255);
    const int k0 = kg << 3;
    const float* src; u16* dst; int orow;
    if (row < 2048)      { src = hs + (long)row * 2048 + k0;          dst = hs_c;   orow = row; }
    else if (row < 4096) { src = Wq + (long)(row - 2048) * 2048 + k0; dst = Wqkv_c; orow = row - 2048; }
    else if (row < 5120) { src = Wk + (long)(row - 4096) * 2048 + k0; dst = Wqkv_c; orow = row - 2048; }
    else if (row < 6144) { src = Wv + (long)(row - 5120) * 2048 + k0; dst = Wqkv_c; orow = row - 2048; }
    else                 { src = Wo + (long)(row - 6144) * 2048 + k0; dst = Wo_c;   orow = row - 6144; }
    float4 a = *(const float4*)src, b = *(const float4*)(src + 4);
    float f[8] = {a.x, a.y, a.z, a.w, b.x, b.y, b.z, b.w};
    us8 h;
#pragma unroll
    for (int j = 0; j < 8; ++j) h[j] = hbits(f[j]);
    const int Kt = k0 >> 5, lg = (k0 >> 3) & 3, r = orow & 127, Rt = orow >> 7;
    const int g = (lg ^ ((r >> 1) & 3)) << 3;
    *(us8*)(dst + ((long)Rt * 64 + Kt) * 4096 + r * 32 + g) = h;
}

// 128x128-tile GEMM, C = A * B^T (fp16 BK=32 blocks), 3-deep LDS buffers,
// counted vmcnt(4) across raw barriers: 2 tiles always in flight, drain only at tail.
// EPI=0: fp32 C write (ldc). EPI=1: fused RMSNorm+RoPE writing fp16 attention buffers.
template<int EPI>
__global__ __launch_bounds__(256) void gemmk(
    const u16* __restrict__ Ap, const u16* __restrict__ Bp, float* __restrict__ Cp,
    int nKt, long ldc,
    const float* __restrict__ cosb, const float* __restrict__ sinb,
    const float* __restrict__ qw, const float* __restrict__ kw,
    u16* __restrict__ state_s, u16* __restrict__ k_s,
    u16* __restrict__ kT_s, u16* __restrict__ vT_s)
{
    const int m0 = blockIdx.y * 128, n0 = blockIdx.x * 128;
    __shared__ char SM[49152];       // A: buf*8192, B: 24576+buf*8192; EPI reuses as u16 LY (32 KB)
    __shared__ float sred[2][128];
    const int tid = threadIdx.x, w = tid >> 6, lane = tid & 63;
    const int wr = (w >> 1) * 64, wc = (w & 1) * 64, fr = lane & 15, fkb = lane >> 4;

    const u16* Ab = Ap + (long)(m0 >> 7) * nKt * 4096;
    const u16* Bb = Bp + (long)(n0 >> 7) * nKt * 4096;

    auto stage = [&](int kt, int buf) {
        const char* sa = (const char*)(Ab + (long)kt * 4096);
        const char* sb = (const char*)(Bb + (long)kt * 4096);
#pragma unroll
        for (int i = 0; i < 2; ++i) {
            gload16(sa + i * 4096 + w * 1024 + lane * 16, SM + buf * 8192 + i * 4096 + w * 1024);
            gload16(sb + i * 4096 + w * 1024 + lane * 16, SM + 24576 + buf * 8192 + i * 4096 + w * 1024);
        }
    };

    f32x4 acc[4][4] = {};
    stage(0, 0);
    if (1 < nKt) stage(1, 1);
    int cur = 0;                 // kt % 3
    for (int kt = 0; kt < nKt; ++kt) {
        // own tile-kt loads landed (tile kt+1's 4 stay in flight), then publish via barrier
        if (kt + 1 < nKt) asm volatile("s_waitcnt vmcnt(4)" ::: "memory");
        else              asm volatile("s_waitcnt vmcnt(0)" ::: "memory");
        __builtin_amdgcn_s_barrier();

        if (kt + 2 < nKt) {
            int b2 = cur + 2; if (b2 >= 3) b2 -= 3;
            stage(kt + 2, b2);   // target buf last read at iter kt-1: certified by barrier above
        }

        const u16* la = (const u16*)(SM + cur * 8192);
        const u16* lb = (const u16*)(SM + 24576 + cur * 8192);
        short8 av[4], bv[4];
#pragma unroll
        for (int m = 0; m < 4; ++m) {
            int r = wr + m * 16 + fr;
            av[m] = *(const short8*)(la + r * 32 + ((fkb ^ ((r >> 1) & 3)) << 3));
        }
#pragma unroll
        for (int n = 0; n < 4; ++n) {
            int r = wc + n * 16 + fr;
            bv[n] = *(const short8*)(lb + r * 32 + ((fkb ^ ((r >> 1) & 3)) << 3));
        }
#pragma unroll
        for (int m = 0; m < 4; ++m)
#pragma unroll
            for (int n = 0; n < 4; ++n)
                acc[m][n] = MFMA16(av[m], bv[n], acc[m][n]);

        ++cur; if (cur >= 3) cur = 0;
    }

    if (EPI == 0) {
#pragma unroll
        for (int m = 0; m < 4; ++m)
#pragma unroll
            for (int j = 0; j < 4; ++j) {
                long row = m0 + wr + m * 16 + fkb * 4 + j;
#pragma unroll
                for (int n = 0; n < 4; ++n)
                    Cp[row * ldc + n0 + wc + n * 16 + fr] = acc[m][n][j];
            }
        return;
    }

    // ---- EPI=1: RMSNorm + RoPE + blocked fp16 scatter ----
    const int b = m0 >> 10;
    const int sbase = m0 & 1023;
    int htype, hidx;
    if (n0 < 2048)      { htype = 0; hidx = n0 >> 7; }
    else if (n0 < 3072) { htype = 1; hidx = (n0 - 2048) >> 7; }
    else                { htype = 2; hidx = (n0 - 3072) >> 7; }

    if (htype == 2) {   // V: straight fp16 transpose-scatter (64-wide attn blocks)
        u16* dTb = vT_s + (long)(b * 8 + hidx) * 131072;
#pragma unroll
        for (int m = 0; m < 4; ++m)
#pragma unroll
            for (int j = 0; j < 4; ++j) {
                int rl = wr + m * 16 + fkb * 4 + j;
                int s = sbase + rl;
#pragma unroll
                for (int n = 0; n < 4; ++n) {
                    int d = wc + n * 16 + fr;
                    dTb[(long)(s >> 6) * 8192 + ((d * 64 + (s & 63)) ^ ((d & 7) << 3))] =
                        hbits(acc[m][n][j]);
                }
            }
        return;
    }

    __syncthreads();    // all staging-LDS reads done before SM reuse
    float ssp[4][4];
#pragma unroll
    for (int m = 0; m < 4; ++m)
#pragma unroll
        for (int j = 0; j < 4; ++j) {
            float s2 = 0.f;
#pragma unroll
            for (int n = 0; n < 4; ++n) s2 += acc[m][n][j] * acc[m][n][j];
            s2 += __shfl_xor(s2, 1); s2 += __shfl_xor(s2, 2);
            s2 += __shfl_xor(s2, 4); s2 += __shfl_xor(s2, 8);
            ssp[m][j] = s2;
        }
    if (fr == 0) {
#pragma unroll
        for (int m = 0; m < 4; ++m)
#pragma unroll
            for (int j = 0; j < 4; ++j)
                sred[w & 1][wr + m * 16 + fkb * 4 + j] = ssp[m][j];
    }
    __syncthreads();

    const float* wv = (htype == 0) ? qw : kw;
    u16* LY = (u16*)SM;   // [128 rows][128 cols] fp16 (32 KB)
#pragma unroll
    for (int m = 0; m < 4; ++m)
#pragma unroll
        for (int j = 0; j < 4; ++j) {
            int rl = wr + m * 16 + fkb * 4 + j;
            float tot = sred[0][rl] + sred[1][rl];
            float rstd = 1.0f / sqrtf(tot * (1.0f / 128.0f) + 1e-6f);
#pragma unroll
            for (int n = 0; n < 4; ++n) {
                int c = wc + n * 16 + fr;
                float y = acc[m][n][j] * rstd * wv[c];
                acc[m][n][j] = y;
                LY[rl * 128 + c] = hbits(y);
            }
        }
    __syncthreads();

    u16* dst; u16* dTb = nullptr;
    if (htype == 0) {
        dst = state_s + (long)(b * 16 + hidx) * 131072 + (long)(sbase >> 7) * 16384;
    } else {
        dst = k_s + (long)(b * 8 + hidx) * 131072 + (long)(sbase >> 7) * 16384;
        dTb = kT_s + (long)(b * 8 + hidx) * 131072;
    }
#pragma unroll
    for (int m = 0; m < 4; ++m)
#pragma unroll
        for (int j = 0; j < 4; ++j) {
            int rl = wr + m * 16 + fkb * 4 + j;
            int s = sbase + rl;
            const float* crow = cosb + (long)(b * 1024 + s) * 128;
            const float* srow = sinb + (long)(b * 1024 + s) * 128;
#pragma unroll
            for (int n = 0; n < 4; ++n) {
                int c = wc + n * 16 + fr;
                float y = acc[m][n][j];
                float prt = h2f(LY[rl * 128 + (c ^ 64)]);
                float cv = crow[c], sv = srow[c];
                float o = (c < 64) ? (y * cv - prt * sv) : (y * cv + prt * sv);
                u16 hv = hbits(o);
                dst[(long)(c >> 6) * 8192 + ((rl * 64 + (c & 63)) ^ ((rl & 7) << 3))] = hv;
                if (htype == 1)
                    dTb[(long)(s >> 6) * 8192 + ((c * 64 + (s & 63)) ^ ((c & 7) << 3))] = hv;
            }
        }
}

// Fused Hopfield step, dual-tile. grid (z=32, g=8).
// STEP<2: PV = kT, write normalized state (64-wide attn layout).
// STEP=2: PV = vT, write stateF (BK=32 GEMM layout) + packed fp16 P + 1/sum.
template<int STEP>
__global__ __launch_bounds__(256) void hopstep(
    const u16* __restrict__ Sin, const u16* __restrict__ Ks,
    const u16* __restrict__ PVs, const float* __restrict__ lb,
    u16* __restrict__ Sout, u16* __restrict__ P_s, float* __restrict__ lsumb)
{
    const int z = blockIdx.x, g = blockIdx.y;
    const int qA = g, qB = 15 - g;
    const int b = z >> 4, h = z & 15;
    const int zp = b * 8 + (h >> 1);
    const float sb = 0.08838834764831845f * __expf(lb[0]);

    __shared__ u16 LK[8192];      // K j-tile, single buffer (16 KB)
    __shared__ u16 LV[2][8192];   // kT/vT s-block double buffer (2 x 16 KB)
    __shared__ u16 LP[8192];      // P: 128 rows (A: 0-63, B: 64-127) x 64 (16 KB)

    const int tid = threadIdx.x, w = tid >> 6, lane = tid & 63;
    const int fr = lane & 15, fkb = lane >> 4;
    const int ql = w * 16 + fkb * 4;

    short8 qvA[4], qvB[4];
    {
        const int rowA = qA * 64 + w * 16 + fr;
        const int MtA = rowA >> 7, rA = rowA & 127, swA = (rA & 7) << 3;
        const u16* QgA = Sin + (long)z * 131072 + (long)MtA * 16384;
        const int rowB = qB * 64 + w * 16 + fr;
        const int MtB = rowB >> 7, rB = rowB & 127, swB = (rB & 7) << 3;
        const u16* QgB = Sin + (long)z * 131072 + (long)MtB * 16384;
#pragma unroll
        for (int ks = 0; ks < 4; ++ks) {
            qvA[ks] = *(const short8*)(QgA + (ks >> 1) * 8192 + ((rA * 64 + (ks & 1) * 32 + fkb * 8) ^ swA));
            qvB[ks] = *(const short8*)(QgB + (ks >> 1) * 8192 + ((rB * 64 + (ks & 1) * 32 + fkb * 8) ^ swB));
        }
    }

    const char* Kzb = (const char*)(Ks + (long)zp * 131072);
    const char* Vz  = (const char*)(PVs + (long)zp * 131072);
    const int jend = 16 - g;

    f32x4 poA[8] = {}, poB[8] = {};
    float lsA[4] = {0.f, 0.f, 0.f, 0.f}, lsB[4] = {0.f, 0.f, 0.f, 0.f};

    auto stageK = [&](int jn) {
#pragma unroll
        for (int i = 0; i < 4; ++i)
            gload16(Kzb + (long)((jn >> 1) * 2 + (i >> 1)) * 16384 + (jn & 1) * 8192 +
                        (i & 1) * 4096 + w * 1024 + lane * 16,
                    (char*)LK + i * 4096 + w * 1024);
    };
    auto stageV = [&](int jn, int buf) {
#pragma unroll
        for (int i = 0; i < 4; ++i)
            gload16(Vz + (long)jn * 16384 + i * 4096 + w * 1024 + lane * 16,
                    (char*)LV[buf] + i * 4096 + w * 1024);
    };

    stageK(0);
    stageV(0, 0);

    int cur = 0;
#pragma unroll 1
    for (int jt = 0; jt < jend; ++jt) {
        __syncthreads();

        const bool actA = (jt <= qA);

        f32x4 psA[4] = {}, psB[4] = {};
#pragma unroll
        for (int n = 0; n < 4; ++n) {
            int rj = n * 16 + fr, swj = (rj & 7) << 3;
#pragma unroll
            for (int ks = 0; ks < 4; ++ks) {
                short8 bk = *(const short8*)(LK + (ks >> 1) * 4096 +
                                             ((rj * 64 + (ks & 1) * 32 + fkb * 8) ^ swj));
                if (actA) psA[n] = MFMA16(qvA[ks], bk, psA[n]);
                psB[n] = MFMA16(qvB[ks], bk, psB[n]);
            }
        }

#pragma unroll
        for (int n = 0; n < 4; ++n) {
            int jc = n * 16 + fr;
            int jglob = jt * 64 + jc;
#pragma unroll
            for (int jj = 0; jj < 4; ++jj) {
                int rl = ql + jj;
                if (actA) {
                    float p = (jglob <= qA * 64 + rl) ? __expf(psA[n][jj] * sb - 4.0f) : 0.f;
                    u16 ph = hbits(p);
                    lsA[jj] += h2f(ph);
                    LP[(rl * 64 + jc) ^ ((rl & 7) << 3)] = ph;
                }
                {
                    float p = (jglob <= qB * 64 + rl) ? __expf(psB[n][jj] * sb - 4.0f) : 0.f;
                    u16 ph = hbits(p);
                    lsB[jj] += h2f(ph);
                    int rb = 64 + rl;
                    LP[(rb * 64 + jc) ^ ((rb & 7) << 3)] = ph;
                }
            }
        }

        __syncthreads();

        if (jt + 1 < jend) { stageK(jt + 1); stageV(jt + 1, cur ^ 1); }

        if (STEP == 2) {
            if (actA) {
                u16* pd = P_s + (long)z * 557056 + 2048L * qA * (qA + 1) + (long)jt * 4096;
                *(us8*)(pd + tid * 16)     = *(const us8*)(LP + tid * 16);
                *(us8*)(pd + tid * 16 + 8) = *(const us8*)(LP + tid * 16 + 8);
            }
            u16* pd = P_s + (long)z * 557056 + 2048L * qB * (qB + 1) + (long)jt * 4096;
            *(us8*)(pd + tid * 16)     = *(const us8*)(LP + 4096 + tid * 16);
            *(us8*)(pd + tid * 16 + 8) = *(const us8*)(LP + 4096 + tid * 16 + 8);
        }

        const int rqA = w * 16 + fr, rqB = 64 + rqA;
#pragma unroll
        for (int ks2 = 0; ks2 < 2; ++ks2) {
            short8 paA = {};
            if (actA) paA = *(const short8*)(LP + ((rqA * 64 + ks2 * 32 + fkb * 8) ^ ((rqA & 7) << 3)));
            short8 paB = *(const short8*)(LP + ((rqB * 64 + ks2 * 32 + fkb * 8) ^ ((rqB & 7) << 3)));
#pragma unroll
            for (int n = 0; n < 8; ++n) {
                int rd = n * 16 + fr;
                short8 vb = *(const short8*)(LV[cur] + ((rd * 64 + ks2 * 32 + fkb * 8) ^ ((rd & 7) << 3)));
                if (actA) poA[n] = MFMA16(paA, vb, poA[n]);
                poB[n] = MFMA16(paB, vb, poB[n]);
            }
        }
        cur ^= 1;
    }

#pragma unroll
    for (int jj = 0; jj < 4; ++jj) {
        float vA = lsA[jj], vB = lsB[jj];
        vA += __shfl_xor(vA, 1); vA += __shfl_xor(vA, 2);
        vA += __shfl_xor(vA, 4); vA += __shfl_xor(vA, 8);
        vB += __shfl_xor(vB, 1); vB += __shfl_xor(vB, 2);
        vB += __shfl_xor(vB, 4); vB += __shfl_xor(vB, 8);
        lsA[jj] = 1.0f / vA;
        lsB[jj] = 1.0f / vB;
    }

    if (STEP == 2) {
        if (fr == 0) {
#pragma unroll
            for (int jj = 0; jj < 4; ++jj) {
                lsumb[(long)z * 1024 + qA * 64 + ql + jj] = lsA[jj];
                lsumb[(long)z * 1024 + qB * 64 + ql + jj] = lsB[jj];
            }
        }
        // stateF writes in BK=32 GEMM layout: [16 Mt][64 Kt] blocks of u16[4096]
#pragma unroll
        for (int jj = 0; jj < 4; ++jj) {
            int rowA = qA * 64 + ql + jj;
            int MtA = b * 8 + (rowA >> 7), rA = rowA & 127;
            int rowB = qB * 64 + ql + jj;
            int MtB = b * 8 + (rowB >> 7), rB = rowB & 127;
#pragma unroll
            for (int n = 0; n < 8; ++n) {
                int d = n * 16 + fr;
                int Kt = h * 4 + (d >> 5), k = d & 31;
                int gA = (((k >> 3) ^ ((rA >> 1) & 3)) << 3) + (k & 7);
                int gB = (((k >> 3) ^ ((rB >> 1) & 3)) << 3) + (k & 7);
                Sout[((long)MtA * 64 + Kt) * 4096 + rA * 32 + gA] =
                    hbits(poA[n][jj] * lsA[jj]);
                Sout[((long)MtB * 64 + Kt) * 4096 + rB * 32 + gB] =
                    hbits(poB[n][jj] * lsB[jj]);
            }
        }
    } else {
        u16* outz = Sout + (long)z * 131072;
#pragma unroll
        for (int jj = 0; jj < 4; ++jj) {
            int rowA = qA * 64 + ql + jj;
            int MoA = rowA >> 7, rA = rowA & 127, swA = (rA & 7) << 3;
            int rowB = qB * 64 + ql + jj;
            int MoB = rowB >> 7, rB = rowB & 127, swB = (rB & 7) << 3;
#pragma unroll
            for (int n = 0; n < 8; ++n) {
                int d = n * 16 + fr;
                outz[(long)(MoA * 2 + (d >> 6)) * 8192 + ((rA * 64 + (d & 63)) ^ swA)] =
                    hbits(poA[n][jj] * lsA[jj]);
                outz[(long)(MoB * 2 + (d >> 6)) * 8192 + ((rB * 64 + (d & 63)) ^ swB)] =
                    hbits(poB[n][jj] * lsB[jj]);
            }
        }
    }
}

// Normalize packed-causal fp16 P -> full-width fp32 attn rows (exact zeros past causal).
__global__ __launch_bounds__(256) void softmaxN(
    const u16* __restrict__ P_s, const float* __restrict__ lsumb, float* __restrict__ attn)
{
    const int row = blockIdx.x;
    const long z = blockIdx.y;
    const int qt = row >> 6, r = row & 63, sw = (r & 7) << 3;
    const float inv = lsumb[z * 1024 + row];
    const int W = (qt + 1) << 6;
    const u16* Pz = P_s + z * 557056 + 2048L * qt * (qt + 1);
    float* rp = attn + (z * 1024 + row) * 1024;
    const int c0 = threadIdx.x * 4;
    float4 o = {0.f, 0.f, 0.f, 0.f};
    if (c0 < W) {
        us4 pv = *(const us4*)(Pz + (long)(c0 >> 6) * 4096 + ((r * 64 + (c0 & 63)) ^ sw));
        o.x = h2f(pv[0]) * inv;
        o.y = h2f(pv[1]) * inv;
        o.z = h2f(pv[2]) * inv;
        o.w = h2f(pv[3]) * inv;
    }
    *(float4*)(rp + c0) = o;
}

extern "C" void kernel_launch(void* const* d_in, const int* in_sizes, int n_in,
                              void* d_out, int out_size, void* d_ws, size_t ws_size,
                              hipStream_t stream)
{
    const float* hs   = (const float*)d_in[0];
    const float* cosb = (const float*)d_in[1];
    const float* sinb = (const float*)d_in[2];
    const float* Wq   = (const float*)d_in[4];
    const float* Wk   = (const float*)d_in[5];
    const float* Wv   = (const float*)d_in[6];
    const float* Wo   = (const float*)d_in[7];
    const float* qw   = (const float*)d_in[8];
    const float* kw   = (const float*)d_in[9];
    const float* lb   = (const float*)d_in[10];

    float* out  = (float*)d_out;
    float* attn = out + 4194304;

    char* ws = (char*)d_ws;
    u16*   hs_c     = (u16*)(ws);                    // 8.4 MB  (BK=32 layout)
    u16*   Wqkv_c   = (u16*)(ws + 8388608L);         // 16.8 MB (BK=32 layout)
    u16*   Wo_c     = (u16*)(ws + 25165824L);        // 8.4 MB  (BK=32 layout)
    u16*   state_s  = (u16*)(ws + 33554432L);        // 8.4 MB  (64-wide attn layout)
    u16*   state2_s = (u16*)(ws + 41943040L);        // 8.4 MB
    u16*   stateF_s = (u16*)(ws + 50331648L);        // 8.4 MB  (BK=32 layout)
    u16*   k_s      = (u16*)(ws + 58720256L);        // 4.2 MB
    u16*   kT_s     = (u16*)(ws + 62914560L);        // 4.2 MB
    u16*   vT_s     = (u16*)(ws + 67108864L);        // 4.2 MB
    u16*   P_s      = (u16*)(ws + 71303168L);        // 35.7 MB (packed causal)
    float* lsumb    = (float*)(ws + 106954752L);     // 131 KB

    cvtall<<<8192, 256, 0, stream>>>(hs, Wq, Wk, Wv, Wo, hs_c, Wqkv_c, Wo_c);

    // QKV projection with fused RMSNorm+RoPE epilogue (K = 64 kt of 32)
    gemmk<1><<<dim3(32, 16), 256, 0, stream>>>(hs_c, Wqkv_c, nullptr, 64, 0L,
        cosb, sinb, qw, kw, state_s, k_s, kT_s, vT_s);

    // t = 0, 1 fused (dual-tile)
    hopstep<0><<<dim3(32, 8), 256, 0, stream>>>(state_s, k_s, kT_s, lb, state2_s, nullptr, nullptr);
    hopstep<0><<<dim3(32, 8), 256, 0, stream>>>(state2_s, k_s, kT_s, lb, state_s, nullptr, nullptr);

    // t = 2 fused (dual-tile): stateF (BK=32 layout) + packed fp16 P + 1/sum
    hopstep<2><<<dim3(32, 8), 256, 0, stream>>>(state_s, k_s, vT_s, lb, stateF_s, P_s, lsumb);

    // attn = P / sum (full width, exact zeros past causal)
    softmaxN<<<dim3(1024, 32), 256, 0, stream>>>(P_s, lsumb, attn);

    // out = stateF . Wo^T
    gemmk<0><<<dim3(16, 16), 256, 0, stream>>>(stateF_s, Wo_c, out, 64, 2048L,
        nullptr, nullptr, nullptr, nullptr, nullptr, nullptr, nullptr, nullptr);
}

// Round 14
// 265.469 us; speedup vs baseline: 1.2434x; 1.2434x over previous
//
#include <hip/hip_runtime.h>

#define DEVI __device__ __forceinline__

typedef __attribute__((ext_vector_type(8))) short short8;
typedef __attribute__((ext_vector_type(4))) float f32x4;
typedef unsigned short u16;
typedef __attribute__((ext_vector_type(4))) u16 us4;
typedef __attribute__((ext_vector_type(8))) u16 us8;

#define MFMA16(a, b, c) __builtin_amdgcn_mfma_f32_16x16x32_f16(a, b, c, 0, 0, 0)

DEVI u16 hbits(float x) {
    union { _Float16 h; u16 u; } cv;
    cv.h = (_Float16)x;
    return cv.u;
}
DEVI float h2f(u16 u) {
    union { u16 u; _Float16 h; } cv;
    cv.u = u;
    return (float)cv.h;
}

DEVI void gload16(const void* g, void* l) {
    __builtin_amdgcn_global_load_lds(
        (const __attribute__((address_space(1))) unsigned int*)g,
        (__attribute__((address_space(3))) unsigned int*)l, 16, 0, 0);
}

// ---- layout ----
// fp16 block: [128 rows][64 k] as u16[8192] (16 KB): idx = (r*64 + k) ^ ((r&7)<<3)
// Buffers are [Mt][Kt] grids of blocks. P tiles are 64x64 (4096 u16), same swizzle.

// All fp32->fp16 blocked conversions in one kernel.
__global__ __launch_bounds__(256) void cvtall(
    const float* __restrict__ hs, const float* __restrict__ Wq, const float* __restrict__ Wk,
    const float* __restrict__ Wv, const float* __restrict__ Wo,
    u16* __restrict__ hs_c, u16* __restrict__ Wqkv_c, u16* __restrict__ Wo_c)
{
    const long t = (long)blockIdx.x * 256 + threadIdx.x;
    const int row = (int)(t >> 8), kg = (int)(t & 255);
    const int k0 = kg << 3;
    const float* src; u16* dst; int orow;
    if (row < 2048)      { src = hs + (long)row * 2048 + k0;          dst = hs_c;   orow = row; }
    else if (row < 4096) { src = Wq + (long)(row - 2048) * 2048 + k0; dst = Wqkv_c; orow = row - 2048; }
    else if (row < 5120) { src = Wk + (long)(row - 4096) * 2048 + k0; dst = Wqkv_c; orow = row - 2048; }
    else if (row < 6144) { src = Wv + (long)(row - 5120) * 2048 + k0; dst = Wqkv_c; orow = row - 2048; }
    else                 { src = Wo + (long)(row - 6144) * 2048 + k0; dst = Wo_c;   orow = row - 6144; }
    float4 a = *(const float4*)src, b = *(const float4*)(src + 4);
    float f[8] = {a.x, a.y, a.z, a.w, b.x, b.y, b.z, b.w};
    us8 h;
#pragma unroll
    for (int j = 0; j < 8; ++j) h[j] = hbits(f[j]);
    const int Kt = k0 >> 6, c = k0 & 63, r = orow & 127, Rt = orow >> 7, sw = (r & 7) << 3;
    *(us8*)(dst + ((long)Rt * 32 + Kt) * 8192 + ((r * 64 + c) ^ sw)) = h;
}

// TM x 128 tile GEMM, C = A * B^T (fp16 blocked operands), BK=64, double-buffered LDS.
// TM=128: 4 waves, 2x2 wave grid (64x64 each) - proven R10/R12 config.
// TM=64:  4 waves, 1x4 wave grid (64x32 each) - doubles grid for occupancy on small M.
// EPI=0: plain fp32 C write (ldc). EPI=1 (TM=128 only): fused RMSNorm+RoPE epilogue.
template<int EPI, int TM>
__global__ __launch_bounds__(256) void gemmk(
    const u16* __restrict__ Ap, const u16* __restrict__ Bp, float* __restrict__ Cp,
    int nKt, long ldc,
    const float* __restrict__ cosb, const float* __restrict__ sinb,
    const float* __restrict__ qw, const float* __restrict__ kw,
    u16* __restrict__ state_s, u16* __restrict__ k_s,
    u16* __restrict__ kT_s, u16* __restrict__ vT_s)
{
    constexpr int ASZ = TM * 128;                 // bytes per A LDS buffer
    constexpr int NW  = (TM == 128) ? 4 : 2;      // n-frags per wave
    const int m0 = blockIdx.y * TM, n0 = blockIdx.x * 128;
    __shared__ char SM[2 * ASZ + 32768];          // A: buf*ASZ | B: 2*ASZ + buf*16384; EPI=1 reuses as LY
    __shared__ float sred[2][128];
    const int tid = threadIdx.x, w = tid >> 6, lane = tid & 63;
    const int wr = (TM == 128) ? (w >> 1) * 64 : 0;
    const int wc = (TM == 128) ? (w & 1) * 64 : w * 32;
    const int fr = lane & 15, fkb = lane >> 4;

    const u16* Ab = Ap + (long)(m0 >> 7) * nKt * 8192 + (long)((m0 >> 6) & 1) * 4096;
    const u16* Bb = Bp + (long)(n0 >> 7) * nKt * 8192;

    auto stage = [&](int kt, int buf) {
        const char* sa = (const char*)(Ab + (long)kt * 8192);
        const char* sb = (const char*)(Bb + (long)kt * 8192);
#pragma unroll
        for (int i = 0; i < TM / 32; ++i)
            gload16(sa + i * 4096 + tid * 16, SM + buf * ASZ + i * 4096 + tid * 16);
#pragma unroll
        for (int i = 0; i < 4; ++i)
            gload16(sb + i * 4096 + tid * 16, SM + 2 * ASZ + buf * 16384 + i * 4096 + tid * 16);
    };

    f32x4 acc[4][NW] = {};
    stage(0, 0);
    int cur = 0;
    for (int kt = 0; kt < nKt; ++kt) {
        __syncthreads();
        if (kt + 1 < nKt) stage(kt + 1, cur ^ 1);

        const u16* la = (const u16*)(SM + cur * ASZ);
        const u16* lb = (const u16*)(SM + 2 * ASZ + cur * 16384);
        short8 av[4][2], bv[NW][2];
#pragma unroll
        for (int m = 0; m < 4; ++m) {
            int r = wr + m * 16 + fr, sw = (r & 7) << 3;
#pragma unroll
            for (int ks = 0; ks < 2; ++ks)
                av[m][ks] = *(const short8*)(la + ((r * 64 + ks * 32 + fkb * 8) ^ sw));
        }
#pragma unroll
        for (int n = 0; n < NW; ++n) {
            int r = wc + n * 16 + fr, sw = (r & 7) << 3;
#pragma unroll
            for (int ks = 0; ks < 2; ++ks)
                bv[n][ks] = *(const short8*)(lb + ((r * 64 + ks * 32 + fkb * 8) ^ sw));
        }
#pragma unroll
        for (int ks = 0; ks < 2; ++ks)
#pragma unroll
            for (int m = 0; m < 4; ++m)
#pragma unroll
                for (int n = 0; n < NW; ++n)
                    acc[m][n] = MFMA16(av[m][ks], bv[n][ks], acc[m][n]);
        cur ^= 1;
    }

    if constexpr (EPI == 0) {
#pragma unroll
        for (int m = 0; m < 4; ++m)
#pragma unroll
            for (int j = 0; j < 4; ++j) {
                long row = m0 + wr + m * 16 + fkb * 4 + j;
#pragma unroll
                for (int n = 0; n < NW; ++n)
                    Cp[row * ldc + n0 + wc + n * 16 + fr] = acc[m][n][j];
            }
        return;
    } else {

    // ---- EPI=1 (TM=128): RMSNorm + RoPE + blocked fp16 scatter ----
    const int b = m0 >> 10;
    const int sbase = m0 & 1023;
    int htype, hidx;
    if (n0 < 2048)      { htype = 0; hidx = n0 >> 7; }
    else if (n0 < 3072) { htype = 1; hidx = (n0 - 2048) >> 7; }
    else                { htype = 2; hidx = (n0 - 3072) >> 7; }

    if (htype == 2) {   // V: straight fp16 transpose-scatter, no norm/rope
        u16* dTb = vT_s + (long)(b * 8 + hidx) * 131072;
#pragma unroll
        for (int m = 0; m < 4; ++m)
#pragma unroll
            for (int j = 0; j < 4; ++j) {
                int rl = wr + m * 16 + fkb * 4 + j;
                int s = sbase + rl;
#pragma unroll
                for (int n = 0; n < NW; ++n) {
                    int d = wc + n * 16 + fr;
                    dTb[(long)(s >> 6) * 8192 + ((d * 64 + (s & 63)) ^ ((d & 7) << 3))] =
                        hbits(acc[m][n][j]);
                }
            }
        return;
    }

    __syncthreads();    // all MFMA LDS reads done before SM reuse
    float ssp[4][4];
#pragma unroll
    for (int m = 0; m < 4; ++m)
#pragma unroll
        for (int j = 0; j < 4; ++j) {
            float s2 = 0.f;
#pragma unroll
            for (int n = 0; n < NW; ++n) s2 += acc[m][n][j] * acc[m][n][j];
            s2 += __shfl_xor(s2, 1); s2 += __shfl_xor(s2, 2);
            s2 += __shfl_xor(s2, 4); s2 += __shfl_xor(s2, 8);
            ssp[m][j] = s2;
        }
    if (fr == 0) {
#pragma unroll
        for (int m = 0; m < 4; ++m)
#pragma unroll
            for (int j = 0; j < 4; ++j)
                sred[w & 1][wr + m * 16 + fkb * 4 + j] = ssp[m][j];
    }
    __syncthreads();

    const float* wv = (htype == 0) ? qw : kw;
    float* LY = (float*)SM;   // [128 rows][128 cols] fp32
#pragma unroll
    for (int m = 0; m < 4; ++m)
#pragma unroll
        for (int j = 0; j < 4; ++j) {
            int rl = wr + m * 16 + fkb * 4 + j;
            float tot = sred[0][rl] + sred[1][rl];
            float rstd = 1.0f / sqrtf(tot * (1.0f / 128.0f) + 1e-6f);
#pragma unroll
            for (int n = 0; n < NW; ++n) {
                int c = wc + n * 16 + fr;
                float y = acc[m][n][j] * rstd * wv[c];
                acc[m][n][j] = y;
                LY[rl * 128 + c] = y;
            }
        }
    __syncthreads();

    u16* dst; u16* dTb = nullptr;
    if (htype == 0) {
        dst = state_s + (long)(b * 16 + hidx) * 131072 + (long)(sbase >> 7) * 16384;
    } else {
        dst = k_s + (long)(b * 8 + hidx) * 131072 + (long)(sbase >> 7) * 16384;
        dTb = kT_s + (long)(b * 8 + hidx) * 131072;
    }
#pragma unroll
    for (int m = 0; m < 4; ++m)
#pragma unroll
        for (int j = 0; j < 4; ++j) {
            int rl = wr + m * 16 + fkb * 4 + j;
            int s = sbase + rl;
            const float* crow = cosb + (long)(b * 1024 + s) * 128;
            const float* srow = sinb + (long)(b * 1024 + s) * 128;
#pragma unroll
            for (int n = 0; n < NW; ++n) {
                int c = wc + n * 16 + fr;
                float y = acc[m][n][j];
                float prt = LY[rl * 128 + (c ^ 64)];
                float cv = crow[c], sv = srow[c];
                float o = (c < 64) ? (y * cv - prt * sv) : (y * cv + prt * sv);
                u16 hv = hbits(o);
                dst[(long)(c >> 6) * 8192 + ((rl * 64 + (c & 63)) ^ ((rl & 7) << 3))] = hv;
                if (htype == 1)
                    dTb[(long)(s >> 6) * 8192 + ((c * 64 + (s & 63)) ^ ((c & 7) << 3))] = hv;
            }
        }
    }
}

// Fused Hopfield step, dual-tile (K/V LDS reads amortized over 2 q-tiles).
// grid (z=32, g=8): block owns q-tiles qA=g, qB=15-g (64 rows each; 16/wave in registers).
// Shifted exp; lsum accumulates fp16-ROUNDED p.
// STEP<2: PV = kT, write normalized state. STEP=2: PV = vT, write stateF + packed fp16 P + 1/sum.
template<int STEP>
__global__ __launch_bounds__(256) void hopstep(
    const u16* __restrict__ Sin, const u16* __restrict__ Ks,
    const u16* __restrict__ PVs, const float* __restrict__ lb,
    u16* __restrict__ Sout, u16* __restrict__ P_s, float* __restrict__ lsumb)
{
    const int z = blockIdx.x, g = blockIdx.y;
    const int qA = g, qB = 15 - g;
    const int b = z >> 4, h = z & 15;
    const int zp = b * 8 + (h >> 1);
    const float sb = 0.08838834764831845f * __expf(lb[0]);

    __shared__ u16 LK[8192];      // K j-tile, single buffer (16 KB)
    __shared__ u16 LV[2][8192];   // kT/vT s-block double buffer (2 x 16 KB)
    __shared__ u16 LP[8192];      // P: 128 rows (A: 0-63, B: 64-127) x 64 (16 KB)

    const int tid = threadIdx.x, w = tid >> 6, lane = tid & 63;
    const int fr = lane & 15, fkb = lane >> 4;
    const int ql = w * 16 + fkb * 4;

    short8 qvA[4], qvB[4];
    {
        const int rowA = qA * 64 + w * 16 + fr;
        const int MtA = rowA >> 7, rA = rowA & 127, swA = (rA & 7) << 3;
        const u16* QgA = Sin + (long)z * 131072 + (long)MtA * 16384;
        const int rowB = qB * 64 + w * 16 + fr;
        const int MtB = rowB >> 7, rB = rowB & 127, swB = (rB & 7) << 3;
        const u16* QgB = Sin + (long)z * 131072 + (long)MtB * 16384;
#pragma unroll
        for (int ks = 0; ks < 4; ++ks) {
            qvA[ks] = *(const short8*)(QgA + (ks >> 1) * 8192 + ((rA * 64 + (ks & 1) * 32 + fkb * 8) ^ swA));
            qvB[ks] = *(const short8*)(QgB + (ks >> 1) * 8192 + ((rB * 64 + (ks & 1) * 32 + fkb * 8) ^ swB));
        }
    }

    const char* Kzb = (const char*)(Ks + (long)zp * 131072);
    const char* Vz  = (const char*)(PVs + (long)zp * 131072);
    const int jend = 16 - g;

    f32x4 poA[8] = {}, poB[8] = {};
    float lsA[4] = {0.f, 0.f, 0.f, 0.f}, lsB[4] = {0.f, 0.f, 0.f, 0.f};

    auto stageK = [&](int jn) {
#pragma unroll
        for (int i = 0; i < 4; ++i)
            gload16(Kzb + (long)((jn >> 1) * 2 + (i >> 1)) * 16384 + (jn & 1) * 8192 +
                        (i & 1) * 4096 + w * 1024 + lane * 16,
                    (char*)LK + i * 4096 + w * 1024);
    };
    auto stageV = [&](int jn, int buf) {
#pragma unroll
        for (int i = 0; i < 4; ++i)
            gload16(Vz + (long)jn * 16384 + i * 4096 + w * 1024 + lane * 16,
                    (char*)LV[buf] + i * 4096 + w * 1024);
    };

    stageK(0);
    stageV(0, 0);

    int cur = 0;
#pragma unroll 1
    for (int jt = 0; jt < jend; ++jt) {
        __syncthreads();

        const bool actA = (jt <= qA);

        f32x4 psA[4] = {}, psB[4] = {};
#pragma unroll
        for (int n = 0; n < 4; ++n) {
            int rj = n * 16 + fr, swj = (rj & 7) << 3;
#pragma unroll
            for (int ks = 0; ks < 4; ++ks) {
                short8 bk = *(const short8*)(LK + (ks >> 1) * 4096 +
                                             ((rj * 64 + (ks & 1) * 32 + fkb * 8) ^ swj));
                if (actA) psA[n] = MFMA16(qvA[ks], bk, psA[n]);
                psB[n] = MFMA16(qvB[ks], bk, psB[n]);
            }
        }

#pragma unroll
        for (int n = 0; n < 4; ++n) {
            int jc = n * 16 + fr;
            int jglob = jt * 64 + jc;
#pragma unroll
            for (int jj = 0; jj < 4; ++jj) {
                int rl = ql + jj;
                if (actA) {
                    float p = (jglob <= qA * 64 + rl) ? __expf(psA[n][jj] * sb - 4.0f) : 0.f;
                    u16 ph = hbits(p);
                    lsA[jj] += h2f(ph);
                    LP[(rl * 64 + jc) ^ ((rl & 7) << 3)] = ph;
                }
                {
                    float p = (jglob <= qB * 64 + rl) ? __expf(psB[n][jj] * sb - 4.0f) : 0.f;
                    u16 ph = hbits(p);
                    lsB[jj] += h2f(ph);
                    int rb = 64 + rl;
                    LP[(rb * 64 + jc) ^ ((rb & 7) << 3)] = ph;
                }
            }
        }

        __syncthreads();

        if (jt + 1 < jend) { stageK(jt + 1); stageV(jt + 1, cur ^ 1); }

        if (STEP == 2) {
            if (actA) {
                u16* pd = P_s + (long)z * 557056 + 2048L * qA * (qA + 1) + (long)jt * 4096;
                *(us8*)(pd + tid * 16)     = *(const us8*)(LP + tid * 16);
                *(us8*)(pd + tid * 16 + 8) = *(const us8*)(LP + tid * 16 + 8);
            }
            u16* pd = P_s + (long)z * 557056 + 2048L * qB * (qB + 1) + (long)jt * 4096;
            *(us8*)(pd + tid * 16)     = *(const us8*)(LP + 4096 + tid * 16);
            *(us8*)(pd + tid * 16 + 8) = *(const us8*)(LP + 4096 + tid * 16 + 8);
        }

        const int rqA = w * 16 + fr, rqB = 64 + rqA;
#pragma unroll
        for (int ks2 = 0; ks2 < 2; ++ks2) {
            short8 paA = {};
            if (actA) paA = *(const short8*)(LP + ((rqA * 64 + ks2 * 32 + fkb * 8) ^ ((rqA & 7) << 3)));
            short8 paB = *(const short8*)(LP + ((rqB * 64 + ks2 * 32 + fkb * 8) ^ ((rqB & 7) << 3)));
#pragma unroll
            for (int n = 0; n < 8; ++n) {
                int rd = n * 16 + fr;
                short8 vb = *(const short8*)(LV[cur] + ((rd * 64 + ks2 * 32 + fkb * 8) ^ ((rd & 7) << 3)));
                if (actA) poA[n] = MFMA16(paA, vb, poA[n]);
                poB[n] = MFMA16(paB, vb, poB[n]);
            }
        }
        cur ^= 1;
    }

#pragma unroll
    for (int jj = 0; jj < 4; ++jj) {
        float vA = lsA[jj], vB = lsB[jj];
        vA += __shfl_xor(vA, 1); vA += __shfl_xor(vA, 2);
        vA += __shfl_xor(vA, 4); vA += __shfl_xor(vA, 8);
        vB += __shfl_xor(vB, 1); vB += __shfl_xor(vB, 2);
        vB += __shfl_xor(vB, 4); vB += __shfl_xor(vB, 8);
        lsA[jj] = 1.0f / vA;
        lsB[jj] = 1.0f / vB;
    }

    if (STEP == 2) {
        if (fr == 0) {
#pragma unroll
            for (int jj = 0; jj < 4; ++jj) {
                lsumb[(long)z * 1024 + qA * 64 + ql + jj] = lsA[jj];
                lsumb[(long)z * 1024 + qB * 64 + ql + jj] = lsB[jj];
            }
        }
#pragma unroll
        for (int jj = 0; jj < 4; ++jj) {
            int rowA = qA * 64 + ql + jj;
            int MtA = b * 8 + (rowA >> 7), rA = rowA & 127, swA = (rA & 7) << 3;
            int rowB = qB * 64 + ql + jj;
            int MtB = b * 8 + (rowB >> 7), rB = rowB & 127, swB = (rB & 7) << 3;
#pragma unroll
            for (int n = 0; n < 8; ++n) {
                int d = n * 16 + fr;
                int Kt = h * 2 + (d >> 6);
                Sout[((long)MtA * 32 + Kt) * 8192 + ((rA * 64 + (d & 63)) ^ swA)] =
                    hbits(poA[n][jj] * lsA[jj]);
                Sout[((long)MtB * 32 + Kt) * 8192 + ((rB * 64 + (d & 63)) ^ swB)] =
                    hbits(poB[n][jj] * lsB[jj]);
            }
        }
    } else {
        u16* outz = Sout + (long)z * 131072;
#pragma unroll
        for (int jj = 0; jj < 4; ++jj) {
            int rowA = qA * 64 + ql + jj;
            int MoA = rowA >> 7, rA = rowA & 127, swA = (rA & 7) << 3;
            int rowB = qB * 64 + ql + jj;
            int MoB = rowB >> 7, rB = rowB & 127, swB = (rB & 7) << 3;
#pragma unroll
            for (int n = 0; n < 8; ++n) {
                int d = n * 16 + fr;
                outz[(long)(MoA * 2 + (d >> 6)) * 8192 + ((rA * 64 + (d & 63)) ^ swA)] =
                    hbits(poA[n][jj] * lsA[jj]);
                outz[(long)(MoB * 2 + (d >> 6)) * 8192 + ((rB * 64 + (d & 63)) ^ swB)] =
                    hbits(poB[n][jj] * lsB[jj]);
            }
        }
    }
}

// Normalize packed-causal fp16 P -> full-width fp32 attn rows (exact zeros past causal).
__global__ __launch_bounds__(256) void softmaxN(
    const u16* __restrict__ P_s, const float* __restrict__ lsumb, float* __restrict__ attn)
{
    const int row = blockIdx.x;
    const long z = blockIdx.y;
    const int qt = row >> 6, r = row & 63, sw = (r & 7) << 3;
    const float inv = lsumb[z * 1024 + row];
    const int W = (qt + 1) << 6;
    const u16* Pz = P_s + z * 557056 + 2048L * qt * (qt + 1);
    float* rp = attn + (z * 1024 + row) * 1024;
    const int c0 = threadIdx.x * 4;
    float4 o = {0.f, 0.f, 0.f, 0.f};
    if (c0 < W) {
        us4 pv = *(const us4*)(Pz + (long)(c0 >> 6) * 4096 + ((r * 64 + (c0 & 63)) ^ sw));
        o.x = h2f(pv[0]) * inv;
        o.y = h2f(pv[1]) * inv;
        o.z = h2f(pv[2]) * inv;
        o.w = h2f(pv[3]) * inv;
    }
    *(float4*)(rp + c0) = o;
}

extern "C" void kernel_launch(void* const* d_in, const int* in_sizes, int n_in,
                              void* d_out, int out_size, void* d_ws, size_t ws_size,
                              hipStream_t stream)
{
    const float* hs   = (const float*)d_in[0];
    const float* cosb = (const float*)d_in[1];
    const float* sinb = (const float*)d_in[2];
    const float* Wq   = (const float*)d_in[4];
    const float* Wk   = (const float*)d_in[5];
    const float* Wv   = (const float*)d_in[6];
    const float* Wo   = (const float*)d_in[7];
    const float* qw   = (const float*)d_in[8];
    const float* kw   = (const float*)d_in[9];
    const float* lb   = (const float*)d_in[10];

    float* out  = (float*)d_out;
    float* attn = out + 4194304;

    char* ws = (char*)d_ws;
    u16*   hs_c     = (u16*)(ws);                    // 8.4 MB
    u16*   Wqkv_c   = (u16*)(ws + 8388608L);         // 16.8 MB
    u16*   Wo_c     = (u16*)(ws + 25165824L);        // 8.4 MB
    u16*   state_s  = (u16*)(ws + 33554432L);        // 8.4 MB
    u16*   state2_s = (u16*)(ws + 41943040L);        // 8.4 MB
    u16*   stateF_s = (u16*)(ws + 50331648L);        // 8.4 MB
    u16*   k_s      = (u16*)(ws + 58720256L);        // 4.2 MB
    u16*   kT_s     = (u16*)(ws + 62914560L);        // 4.2 MB
    u16*   vT_s     = (u16*)(ws + 67108864L);        // 4.2 MB
    u16*   P_s      = (u16*)(ws + 71303168L);        // 35.7 MB (packed causal)
    float* lsumb    = (float*)(ws + 106954752L);     // 131 KB

    cvtall<<<8192, 256, 0, stream>>>(hs, Wq, Wk, Wv, Wo, hs_c, Wqkv_c, Wo_c);

    // QKV projection with fused RMSNorm+RoPE epilogue (proven TM=128 config)
    gemmk<1, 128><<<dim3(32, 16), 256, 0, stream>>>(hs_c, Wqkv_c, nullptr, 32, 0L,
        cosb, sinb, qw, kw, state_s, k_s, kT_s, vT_s);

    // t = 0, 1 fused (dual-tile)
    hopstep<0><<<dim3(32, 8), 256, 0, stream>>>(state_s, k_s, kT_s, lb, state2_s, nullptr, nullptr);
    hopstep<0><<<dim3(32, 8), 256, 0, stream>>>(state2_s, k_s, kT_s, lb, state_s, nullptr, nullptr);

    // t = 2 fused (dual-tile): stateF + packed fp16 P + 1/sum
    hopstep<2><<<dim3(32, 8), 256, 0, stream>>>(state_s, k_s, vT_s, lb, stateF_s, P_s, lsumb);

    // attn = P / sum (full width, exact zeros past causal)
    softmaxN<<<dim3(1024, 32), 256, 0, stream>>>(P_s, lsumb, attn);

    // out = stateF . Wo^T  (TM=64: 512 blocks -> 2-3 blocks/CU instead of 1)
    gemmk<0, 64><<<dim3(16, 32), 256, 0, stream>>>(stateF_s, Wo_c, out, 32, 2048L,
        nullptr, nullptr, nullptr, nullptr, nullptr, nullptr, nullptr, nullptr);
}